// Round 4
// baseline (551.729 us; speedup 1.0000x reference)
//
#include <hip/hip_runtime.h>
#include <math.h>

#define BB 32
#define CC 512
#define DD 4096
#define HH 128

typedef float f4_native __attribute__((ext_vector_type(4)));

// ---------------------------------------------------------------------------
// float4 cross-lane xor shuffle (component-wise)
// ---------------------------------------------------------------------------
__device__ __forceinline__ float4 shfl_xor_f4(float4 v, int mask) {
    float4 r;
    r.x = __shfl_xor(v.x, mask, 64);
    r.y = __shfl_xor(v.y, mask, 64);
    r.z = __shfl_xor(v.z, mask, 64);
    r.w = __shfl_xor(v.w, mask, 64);
    return r;
}

// ---------------------------------------------------------------------------
// Kernel 1: bitwise replica of np.mean(x, axis=2) fp32 — numpy pairwise-sum
// tree, float4 loads. Verified bit-exact (absmax 0.0 three rounds running).
// Also streams all 256 MiB of x through L3 so it is warm for gather.
// ---------------------------------------------------------------------------
__global__ __launch_bounds__(256) void pool_mean_np(const float* __restrict__ x,
                                                    float* __restrict__ pooled) {
    const int wave = threadIdx.x >> 6;
    const int l = threadIdx.x & 63;
    const int row = blockIdx.x * 4 + wave;
    const float4* __restrict__ xr = (const float4*)(x + (size_t)row * DD);

    const int bq = l >> 4;        // block within quad (0..3)
    const int cp = (l >> 2) & 3;  // chunk pair (0..3)
    const int p  = l & 3;         // f4 position within chunk (0..3)

    float q8[8];
#pragma unroll
    for (int it = 0; it < 8; ++it) {
        const int blk = 4 * it + bq;
        const int ia = blk * 32 + 8 * cp + p;   // chunk 2cp, elems 4p..4p+3
        float4 A = xr[ia];
        float4 B = xr[ia + 4];                  // chunk 2cp+1, same elems
        float4 u;
        u.x = A.x + B.x; u.y = A.y + B.y; u.z = A.z + B.z; u.w = A.w + B.w;
        float4 t;
        t = shfl_xor_f4(u, 4); u.x += t.x; u.y += t.y; u.z += t.z; u.w += t.w;
        t = shfl_xor_f4(u, 8); u.x += t.x; u.y += t.y; u.z += t.z; u.w += t.w;
        t = shfl_xor_f4(u, 2); u.x += t.x; u.y += t.y; u.z += t.z; u.w += t.w;
        t = shfl_xor_f4(u, 1); u.x += t.x; u.y += t.y; u.z += t.z; u.w += t.w;
        float h0 = u.x + u.z;                   // stride 2
        float h1 = u.y + u.w;
        float S = h0 + h1;                      // stride 1 -> block sum
        S += __shfl_xor(S, 16, 64);
        S += __shfl_xor(S, 32, 64);
        q8[it] = S;
    }
    float t01 = q8[0] + q8[1], t23 = q8[2] + q8[3];
    float t45 = q8[4] + q8[5], t67 = q8[6] + q8[7];
    float tot = (t01 + t23) + (t45 + t67);
    if (l == 0) pooled[row] = tot / 4096.0f;    // /2^12: exact
}

// ---------------------------------------------------------------------------
// Kernel 2: fp32 MLP (bit-identical fmaf chains, LDS-staged weight panels,
// verified bit-exact) + NEW: in-LDS cycle decomposition of the permutation.
// Emits, per batch:
//   seq[pos]   : row indices in cycle order (cycles ordered by min element)
//   snx[pos]   : sigma(seq[pos])  (== seq[pos+1] except at cycle wrap)
//   segtab[si] : pos | (len<<16), segments of <=8 outputs, each within one
//                cycle  ->  gather needs len+1 row loads for len outputs
//   nseg[b]    : segment count
// Decomposition: each thread walks its own cycle in LDS (rep = min element,
// own rank, cycle length), then two Hillis-Steele scans assign dense seq
// positions (prefix of cycle lengths over reps) and dense segment indices
// (prefix of ceil(L/8) over reps).
// ---------------------------------------------------------------------------
__global__ __launch_bounds__(512) void mlp_sort_np(
    const float* __restrict__ pooled,
    const float* __restrict__ W1, const float* __restrict__ b1,
    const float* __restrict__ W2, const float* __restrict__ b2,
    int* __restrict__ seqg, int* __restrict__ snxg,
    int* __restrict__ segtab, int* __restrict__ nseg) {
    const int b = blockIdx.x;
    const int t = threadIdx.x;

    __shared__ float p[CC];
    __shared__ float h[HH];
    __shared__ float s[CC];
    __shared__ float wbuf[8704];  // max(W1 panel 8192, W2 panel 512*17=8704)
    __shared__ int ordl[CC];      // sigma: ordl[i] = channel at rank i
    __shared__ int scanb[CC];     // scan scratch (reused for both scans)

    p[t] = pooled[b * CC + t];

    // ---- Layer 1: panels of 64 columns; u over panels 0..3, v over 4..7
    float u = 0.0f, v = 0.0f;
    const float4* __restrict__ W1v = (const float4*)W1;
#pragma unroll 1
    for (int pi = 0; pi < 8; ++pi) {
        const int k0 = pi * 64;
        __syncthreads();                        // previous panel consumed
#pragma unroll
        for (int si = 0; si < 4; ++si) {        // 2048 f4 = 4 per thread
            const int f = t + 512 * si;
            const int r = f >> 4;               // row 0..127
            const int j = f & 15;               // f4 within row-panel
            float4 val = W1v[r * 128 + (k0 >> 2) + j];
            const int base = r << 6;
            const int sw = r & 31;
            wbuf[base + ((4 * j + 0) ^ sw)] = val.x;
            wbuf[base + ((4 * j + 1) ^ sw)] = val.y;
            wbuf[base + ((4 * j + 2) ^ sw)] = val.z;
            wbuf[base + ((4 * j + 3) ^ sw)] = val.w;
        }
        __syncthreads();
        if (t < HH) {
            const int base = t << 6;
            const int sw = t & 31;
            float acc = (pi < 4) ? u : v;
            for (int kk = 0; kk < 64; ++kk)
                acc = fmaf(p[k0 + kk], wbuf[base + (kk ^ sw)], acc);
            if (pi < 4) u = acc; else v = acc;
        }
    }
    if (t < HH) {
        float acc = u + v;                      // K-panel combine (256+256)
        float hv = acc + b1[t];
        h[t] = (hv >= 0.0f) ? hv : 0.01f * hv;  // LeakyReLU(0.01)
    }

    // ---- Layer 2: panels of 16 columns, pad-17 LDS rows
    float acc2 = 0.0f;
    const float4* __restrict__ W2v = (const float4*)W2;
#pragma unroll 1
    for (int pi = 0; pi < 8; ++pi) {
        const int k0 = pi * 16;
        __syncthreads();                        // orders h-write & wbuf reuse
#pragma unroll
        for (int si = 0; si < 4; ++si) {        // 2048 f4 = 4 per thread
            const int f = t + 512 * si;
            const int r = f >> 2;               // row 0..511
            const int j = f & 3;                // f4 within row-panel
            float4 val = W2v[r * 32 + (k0 >> 2) + j];
            float* dst = &wbuf[r * 17 + 4 * j];
            dst[0] = val.x; dst[1] = val.y; dst[2] = val.z; dst[3] = val.w;
        }
        __syncthreads();
        const float* __restrict__ wrow = &wbuf[t * 17];
#pragma unroll
        for (int kk = 0; kk < 16; ++kk)
            acc2 = fmaf(h[k0 + kk], wrow[kk], acc2);
    }
    {
        float z = acc2 + b2[t];
        float e = (float)exp(-(double)z);       // correctly-rounded fp32 exp
        s[t] = 1.0f / (1.0f + e);
    }
    __syncthreads();

    // ---- stable descending rank-count == jnp.argsort(-scores)
    const float mine = s[t];
    int rank = 0;
    for (int j = 0; j < CC; ++j) {
        float vv = s[j];
        rank += (vv > mine) || (vv == mine && j < t);
    }
    ordl[rank] = t;                 // sigma(rank) = channel t
    __syncthreads();

    // ---- cycle walk: thread t walks its own cycle
    int m = t, tm = 0, L = 1;
    {
        int c = ordl[t];
        int steps = 1;
        while (c != t) {
            if (c < m) { m = c; tm = steps; }
            c = ordl[c];
            ++L; ++steps;
        }
    }
    const int r = tm ? (L - tm) : 0;            // rank of t within cycle
    const int isrep = (m == t);

    // ---- scan 1: dense seq positions (prefix of cycle lengths over reps)
    scanb[t] = isrep ? L : 0;
    __syncthreads();
    for (int off = 1; off < CC; off <<= 1) {
        int v2 = scanb[t];
        if (t >= off) v2 += scanb[t - off];
        __syncthreads();
        scanb[t] = v2;
        __syncthreads();
    }
    const int pos = (scanb[m] - L) + r;         // base of my cycle + my rank
    __syncthreads();

    // ---- scan 2: dense segment indices (prefix of ceil(L/8) over reps)
    scanb[t] = isrep ? ((L + 7) >> 3) : 0;
    __syncthreads();
    for (int off = 1; off < CC; off <<= 1) {
        int v2 = scanb[t];
        if (t >= off) v2 += scanb[t - off];
        __syncthreads();
        scanb[t] = v2;
        __syncthreads();
    }
    const int segbase = scanb[m] - ((L + 7) >> 3);

    seqg[b * CC + pos] = t;
    snxg[b * CC + pos] = ordl[t];
    if ((r & 7) == 0) {
        const int len = (L - r < 8) ? (L - r) : 8;
        segtab[b * CC + segbase + (r >> 3)] = pos | (len << 16);
    }
    if (t == CC - 1) nseg[b] = scanb[CC - 1];
}

// ---------------------------------------------------------------------------
// Kernel 3: cycle-segment gather. A block processes a segment of len<=8
// outputs lying within one permutation cycle: out[seq[p+j]] =
// x[seq[p+j]] + x[snx[p+j]], where snx[p+j] == seq[p+j+1] for j<len-1 —
// so the shared row stays in registers: len+1 row loads for len outputs
// (read traffic 512 -> ~291 MiB). NT stores (out never read). Grid is
// XCD-grouped: batch b's segments all land on XCD b>>2 for L2 locality.
// Bit-exact: each output row is exactly one fp32 add, same operands.
// ---------------------------------------------------------------------------
__global__ __launch_bounds__(256) void gather_cycle(
    const float* __restrict__ x, const int* __restrict__ seqg,
    const int* __restrict__ snxg, const int* __restrict__ segtab,
    const int* __restrict__ nseg, float* __restrict__ out) {
    const int bid = blockIdx.x;                 // 4096 blocks
    const int xcd = bid & 7;
    const int k = bid >> 3;                     // 0..511
    const int b = xcd * 4 + (k >> 7);           // 4 batches per XCD
    const int s0 = k & 127;
    const int ns = nseg[b];
    const size_t xb = (size_t)b * CC * DD;
    const int t = threadIdx.x;

    for (int sidx = s0; sidx < ns; sidx += 128) {
        const int e = segtab[b * CC + sidx];
        const int pos = e & 0xffff;
        const int len = e >> 16;
        const int gp = b * CC + pos;

        const int r0 = seqg[gp];
        const float4* __restrict__ xr = (const float4*)(x + xb + (size_t)r0 * DD);
        float4 c0 = xr[t], c1 = xr[t + 256], c2 = xr[t + 512], c3 = xr[t + 768];

        for (int j = 0; j < len; ++j) {
            const int orow = seqg[gp + j];
            const int srow = snxg[gp + j];
            const float4* __restrict__ xn =
                (const float4*)(x + xb + (size_t)srow * DD);
            float4 n0 = xn[t], n1 = xn[t + 256], n2 = xn[t + 512],
                   n3 = xn[t + 768];
            f4_native* __restrict__ o =
                (f4_native*)(out + xb + (size_t)orow * DD);
            f4_native o0, o1, o2, o3;
            o0.x = c0.x + n0.x; o0.y = c0.y + n0.y; o0.z = c0.z + n0.z; o0.w = c0.w + n0.w;
            o1.x = c1.x + n1.x; o1.y = c1.y + n1.y; o1.z = c1.z + n1.z; o1.w = c1.w + n1.w;
            o2.x = c2.x + n2.x; o2.y = c2.y + n2.y; o2.z = c2.z + n2.z; o2.w = c2.w + n2.w;
            o3.x = c3.x + n3.x; o3.y = c3.y + n3.y; o3.z = c3.z + n3.z; o3.w = c3.w + n3.w;
            __builtin_nontemporal_store(o0, &o[t]);
            __builtin_nontemporal_store(o1, &o[t + 256]);
            __builtin_nontemporal_store(o2, &o[t + 512]);
            __builtin_nontemporal_store(o3, &o[t + 768]);
            c0 = n0; c1 = n1; c2 = n2; c3 = n3;  // snx[p+j]==seq[p+j+1] in-cycle
        }
    }
}

extern "C" void kernel_launch(void* const* d_in, const int* in_sizes, int n_in,
                              void* d_out, int out_size, void* d_ws,
                              size_t ws_size, hipStream_t stream) {
    const float* x  = (const float*)d_in[0];
    const float* W1 = (const float*)d_in[1];
    const float* b1 = (const float*)d_in[2];
    const float* W2 = (const float*)d_in[3];
    const float* b2 = (const float*)d_in[4];
    float* out = (float*)d_out;

    // workspace layout (bytes):
    //   pooled 0..64K | seq 64K..128K | snx 128K..192K | segtab 192K..256K
    //   nseg 256K..256K+128
    char* ws = (char*)d_ws;
    float* pooled = (float*)ws;
    int* seqg   = (int*)(ws + (size_t)64 * 1024);
    int* snxg   = (int*)(ws + (size_t)128 * 1024);
    int* segtab = (int*)(ws + (size_t)192 * 1024);
    int* nseg   = (int*)(ws + (size_t)256 * 1024);

    pool_mean_np<<<BB * CC / 4, 256, 0, stream>>>(x, pooled);
    mlp_sort_np<<<BB, 512, 0, stream>>>(pooled, W1, b1, W2, b2,
                                        seqg, snxg, segtab, nseg);
    gather_cycle<<<4096, 256, 0, stream>>>(x, seqg, snxg, segtab, nseg, out);
}